// Round 5
// baseline (377.546 us; speedup 1.0000x reference)
//
#include <hip/hip_runtime.h>
#include <hip/hip_bf16.h>
#include <math.h>

#define HID 128
#define ODIM 64
#define NBUCK_MAX 64
#define CAPA 96

typedef __bf16 bf16x8 __attribute__((ext_vector_type(8)));
typedef float f32x4 __attribute__((ext_vector_type(4)));

union FragU {
  unsigned u[4];
  bf16x8 v;
};

// ---------------------------------------------------------------------------
// bf16 helpers (RNE)
// ---------------------------------------------------------------------------
__device__ inline unsigned pack_bf16(float a, float b) {
  unsigned ua = __float_as_uint(a), ub = __float_as_uint(b);
  ua += 0x7fffu + ((ua >> 16) & 1u);
  ub += 0x7fffu + ((ub >> 16) & 1u);
  return (ua >> 16) | (ub & 0xffff0000u);
}
__device__ inline float bf16_lo(unsigned u) { return __uint_as_float(u << 16); }
__device__ inline float bf16_hi(unsigned u) {
  return __uint_as_float(u & 0xffff0000u);
}
__device__ inline unsigned short bf16_of(float v) {
  unsigned uv = __float_as_uint(v);
  uv += 0x7fffu + ((uv >> 16) & 1u);
  return (unsigned short)(uv >> 16);
}

// ---------------------------------------------------------------------------
// Detect whether edge_index buffer is int64 (JAX x64 on) or int32.
// ---------------------------------------------------------------------------
__global__ void detect_idx_kernel(const unsigned int* __restrict__ ei_words,
                                  int* __restrict__ flag) {
  int t = threadIdx.x;  // 64 threads
  unsigned int v = ei_words[2 * t + 1];
  unsigned long long b = __ballot(v == 0u);
  if (t == 0) *flag = (b == 0xFFFFFFFFFFFFFFFFull) ? 1 : 0;
}

__device__ inline int edge_val(const void* ei, int is64, long long idx) {
  if (is64) return (int)((const long long*)ei)[idx];
  return ((const int*)ei)[idx];
}

// ---------------------------------------------------------------------------
// CSR pass A0: histogram of col>>10 into nbuck coarse buckets (LDS-staged).
// ---------------------------------------------------------------------------
__global__ __launch_bounds__(256) void bucket_count_kernel(
    const void* __restrict__ ei, int E, const int* __restrict__ flag,
    unsigned* __restrict__ bucket_cnt, int nbuck) {
  __shared__ unsigned h[NBUCK_MAX];
  for (int i = threadIdx.x; i < nbuck; i += 256) h[i] = 0;
  __syncthreads();
  int is64 = *flag;
  for (int e = blockIdx.x * 256 + threadIdx.x; e < E; e += gridDim.x * 256) {
    int col = edge_val(ei, is64, (long long)E + e);
    atomicAdd(&h[col >> 10], 1u);
  }
  __syncthreads();
  for (int i = threadIdx.x; i < nbuck; i += 256)
    if (h[i]) atomicAdd(&bucket_cnt[i], h[i]);
}

// ---------------------------------------------------------------------------
// CSR bucket scan (one wave): bucket_base = exclusive scan; init gcursor.
// bucket regions in edge space ARE the final CSR regions (buckets are
// col-contiguous). Also writes offsets[n] = E.
// ---------------------------------------------------------------------------
__global__ void bucket_scan_kernel(const unsigned* __restrict__ bucket_cnt,
                                   unsigned* __restrict__ bucket_base,
                                   unsigned* __restrict__ gcursor,
                                   unsigned* __restrict__ offsets, int nbuck,
                                   int n, int E) {
  int t = threadIdx.x;  // 64 threads
  unsigned v = (t < nbuck) ? bucket_cnt[t] : 0u;
  unsigned incl = v;
#pragma unroll
  for (int d = 1; d < 64; d <<= 1) {
    unsigned u = __shfl_up(incl, d, 64);
    if (t >= d) incl += u;
  }
  unsigned ex = incl - v;
  if (t < nbuck) {
    bucket_base[t] = ex;
    gcursor[t] = ex;
  }
  if (t == 0) {
    bucket_base[nbuck] = (unsigned)E;
    offsets[n] = (unsigned)E;
  }
}

// ---------------------------------------------------------------------------
// CSR pass A1: bin edges into LDS buckets per 1024-edge chunk, flush each
// bucket with one global atomic + coalesced burst into recbuf's bucket
// region. rec = (col&1023)<<17 | row  (needs N <= 131072).
// ---------------------------------------------------------------------------
__global__ __launch_bounds__(256) void bin_scatter_kernel(
    const void* __restrict__ ei, int E, const int* __restrict__ flag,
    unsigned* __restrict__ gcursor, unsigned* __restrict__ recbuf, int nbuck) {
  __shared__ unsigned bcnt[NBUCK_MAX];
  __shared__ unsigned bins[NBUCK_MAX][CAPA];
  int is64 = *flag;
  int tid = threadIdx.x;
  int wave = tid >> 6, lane = tid & 63;
  for (int chunk0 = blockIdx.x * 1024; chunk0 < E; chunk0 += gridDim.x * 1024) {
    for (int i = tid; i < nbuck; i += 256) bcnt[i] = 0;
    __syncthreads();
    int nc = min(1024, E - chunk0);
    for (int j = tid; j < nc; j += 256) {
      int e = chunk0 + j;
      int row = edge_val(ei, is64, e);
      int col = edge_val(ei, is64, (long long)E + e);
      int b = col >> 10;
      unsigned rec = ((unsigned)(col & 1023) << 17) | (unsigned)row;
      unsigned p = atomicAdd(&bcnt[b], 1u);
      if (p < CAPA) {
        bins[b][p] = rec;
      } else {  // overflow spill (statistically never for uniform cols)
        unsigned gp = atomicAdd(&gcursor[b], 1u);
        recbuf[gp] = rec;
      }
    }
    __syncthreads();
    for (int b = wave; b < nbuck; b += 4) {
      unsigned cnt = min(bcnt[b], (unsigned)CAPA);
      if (cnt == 0) continue;
      unsigned base = 0;
      if (lane == 0) base = atomicAdd(&gcursor[b], cnt);
      base = __shfl(base, 0, 64);
      for (unsigned k = lane; k < cnt; k += 64) recbuf[base + k] = bins[b][k];
    }
    __syncthreads();
  }
}

// ---------------------------------------------------------------------------
// CSR pass B: one block per bucket. LDS histogram over the bucket's 1024
// cols -> LDS scan -> offsets/dinv (coalesced) -> scatter rows into the
// bucket's contiguous ebuf window (L2-resident) via LDS cursors.
// ---------------------------------------------------------------------------
__global__ __launch_bounds__(256) void csr_build_kernel(
    const unsigned* __restrict__ recbuf,
    const unsigned* __restrict__ bucket_base, unsigned* __restrict__ offsets,
    float* __restrict__ dinv, int* __restrict__ ebuf, int n) {
  __shared__ unsigned hist[1024];
  __shared__ unsigned cur[1024];
  __shared__ unsigned wsum[4];
  int b = blockIdx.x;
  unsigned s = bucket_base[b], e = bucket_base[b + 1];
  int col0 = b << 10;
  int ncols = min(1024, n - col0);
  int tid = threadIdx.x;
  for (int i = tid; i < 1024; i += 256) hist[i] = 0;
  __syncthreads();
  for (unsigned t = s + tid; t < e; t += 256)
    atomicAdd(&hist[recbuf[t] >> 17], 1u);
  __syncthreads();
  unsigned c4[4];
  unsigned tsum = 0;
#pragma unroll
  for (int j = 0; j < 4; ++j) {
    c4[j] = hist[tid * 4 + j];
    tsum += c4[j];
  }
  unsigned incl = tsum;
#pragma unroll
  for (int d = 1; d < 64; d <<= 1) {
    unsigned u = __shfl_up(incl, d, 64);
    if ((tid & 63) >= d) incl += u;
  }
  int wave = tid >> 6;
  if ((tid & 63) == 63) wsum[wave] = incl;
  __syncthreads();
  unsigned ex = incl - tsum;
  for (int w = 0; w < wave; ++w) ex += wsum[w];
#pragma unroll
  for (int j = 0; j < 4; ++j) {
    int c = tid * 4 + j;
    unsigned exv = ex;
    ex += c4[j];
    cur[c] = exv;
    if (c < ncols) {
      offsets[col0 + c] = s + exv;
      dinv[col0 + c] = rsqrtf((float)(1u + c4[j]));
    }
  }
  __syncthreads();
  for (unsigned t = s + tid; t < e; t += 256) {
    unsigned rec = recbuf[t];
    unsigned c = rec >> 17;
    unsigned p = atomicAdd(&cur[c], 1u);
    ebuf[s + p] = (int)(rec & 0x1FFFFu);
  }
}

// ---------------------------------------------------------------------------
// Split W (f32, [128][NC] row-major) into bf16 hi/lo fragments in MFMA
// fragment order (see mfma_gemm_kernel).
// ---------------------------------------------------------------------------
__global__ void wfrag_kernel(const float* __restrict__ W,
                             unsigned* __restrict__ Whi,
                             unsigned* __restrict__ Wlo, int NC) {
  int total = (NC / 16) * 4 * 64;
  for (int e = blockIdx.x * blockDim.x + threadIdx.x; e < total;
       e += gridDim.x * blockDim.x) {
    int lane = e & 63;
    int s = (e >> 6) & 3;
    int t = e >> 8;
    int g = lane >> 4, c = lane & 15;
    int col = t * 16 + c;
    unsigned hw[4], lw[4];
#pragma unroll
    for (int j = 0; j < 4; ++j) {
      float a = W[(32 * s + g * 8 + 2 * j) * NC + col];
      float b = W[(32 * s + g * 8 + 2 * j + 1) * NC + col];
      unsigned h = pack_bf16(a, b);
      hw[j] = h;
      lw[j] = pack_bf16(a - bf16_lo(h), b - bf16_hi(h));
    }
    *(uint4*)&Whi[(size_t)e * 4] = make_uint4(hw[0], hw[1], hw[2], hw[3]);
    *(uint4*)&Wlo[(size_t)e * 4] = make_uint4(lw[0], lw[1], lw[2], lw[3]);
  }
}

// ---------------------------------------------------------------------------
// Split-bf16 MFMA GEMM:  out[M,NC] = A[M,128] @ W[128,NC], fp32-quality via
// D = Ah*Wh + Ah*Wl + Al*Wh. 4 waves = 64 rows x 64 cols; no LDS.
// ---------------------------------------------------------------------------
template <int NC, int RELU, int OBF16, int SIG0>
__global__ __launch_bounds__(256, 4) void mfma_gemm_kernel(
    const float* __restrict__ A, const unsigned* __restrict__ Whi,
    const unsigned* __restrict__ Wlo, const float* __restrict__ bias,
    const float* __restrict__ row_scale, void* __restrict__ out, int M) {
  int wave = threadIdx.x >> 6, lane = threadIdx.x & 63;
  int g = lane >> 4, c = lane & 15;
  int tiles_m = (M + 63) >> 6;
  int tiles_total = tiles_m * (NC / 64);
  for (int tid = blockIdx.x; tid < tiles_total; tid += gridDim.x) {
    int mt = tid % tiles_m;
    int half = tid / tiles_m;
    int r0 = mt * 64 + wave * 16;
    int rowc = min(r0 + c, M - 1);  // A-frag row = lane&15
    const float* ap = A + (size_t)rowc * 128 + g * 8;
    f32x4 fa[8];
#pragma unroll
    for (int s = 0; s < 4; ++s) {
      fa[2 * s] = *(const f32x4*)(ap + 32 * s);
      fa[2 * s + 1] = *(const f32x4*)(ap + 32 * s + 4);
    }
    f32x4 acc[4];
#pragma unroll
    for (int t = 0; t < 4; ++t) acc[t] = (f32x4){0.f, 0.f, 0.f, 0.f};
#pragma unroll
    for (int s = 0; s < 4; ++s) {
      FragU ah, al;
#pragma unroll
      for (int j = 0; j < 2; ++j) {
        f32x4 p = fa[2 * s + j];
        unsigned h0 = pack_bf16(p[0], p[1]);
        unsigned h1 = pack_bf16(p[2], p[3]);
        ah.u[2 * j] = h0;
        ah.u[2 * j + 1] = h1;
        al.u[2 * j] = pack_bf16(p[0] - bf16_lo(h0), p[1] - bf16_hi(h0));
        al.u[2 * j + 1] = pack_bf16(p[2] - bf16_lo(h1), p[3] - bf16_hi(h1));
      }
#pragma unroll
      for (int tl = 0; tl < 4; ++tl) {
        int e = ((half * 4 + tl) * 4 + s) * 64 + lane;
        FragU wh, wl;
        *(uint4*)wh.u = *(const uint4*)&Whi[(size_t)e * 4];
        *(uint4*)wl.u = *(const uint4*)&Wlo[(size_t)e * 4];
        acc[tl] = __builtin_amdgcn_mfma_f32_16x16x32_bf16(ah.v, wh.v, acc[tl],
                                                          0, 0, 0);
        acc[tl] = __builtin_amdgcn_mfma_f32_16x16x32_bf16(ah.v, wl.v, acc[tl],
                                                          0, 0, 0);
        acc[tl] = __builtin_amdgcn_mfma_f32_16x16x32_bf16(al.v, wh.v, acc[tl],
                                                          0, 0, 0);
      }
    }
    float rs[4];
    if (row_scale) {
#pragma unroll
      for (int r = 0; r < 4; ++r) rs[r] = row_scale[min(r0 + g * 4 + r, M - 1)];
    }
#pragma unroll
    for (int tl = 0; tl < 4; ++tl) {
      int colg = half * 64 + tl * 16 + c;
      float bv = bias ? bias[colg] : 0.f;
#pragma unroll
      for (int rg = 0; rg < 4; ++rg) {
        int r = r0 + g * 4 + rg;
        if (r < M) {
          float v = acc[tl][rg] + bv;
          if (RELU) v = fmaxf(v, 0.f);
          if (row_scale) v *= rs[rg];
          if (SIG0 && colg == 0) v = 1.f / (1.f + __expf(-v));
          if (OBF16) {
            ((unsigned short*)out)[(size_t)r * 128 + colg] = bf16_of(v);
          } else {
            ((float*)out)[(size_t)r * NC + colg] = v;
          }
        }
      }
    }
  }
}

// ---------------------------------------------------------------------------
// Aggregation: one wave per node. xwb is bf16 [N][128] (packed u32 [N][64]),
// PRE-SCALED by dinv[src]. h2 = relu((xwb[i] + sum_j xwb[j]) * dinv[i] + bg).
// ---------------------------------------------------------------------------
__global__ __launch_bounds__(256) void agg_kernel(
    const unsigned* __restrict__ xwb, const float* __restrict__ dinv,
    const unsigned int* __restrict__ offsets, const int* __restrict__ ebuf,
    const float* __restrict__ bg, float* __restrict__ h2, int n) {
  int lane = threadIdx.x & 63;
  int wid = (blockIdx.x * blockDim.x + threadIdx.x) >> 6;
  int nw = (gridDim.x * blockDim.x) >> 6;
  float2 bgv = ((const float2*)bg)[lane];
  for (int i = wid; i < n; i += nw) {
    float di = dinv[i];
    unsigned int s = offsets[i];
    unsigned int e = offsets[i + 1];
    unsigned uself = xwb[(size_t)i * 64 + lane];
    float ax = bf16_lo(uself), ay = bf16_hi(uself);
    unsigned int t = s;
    for (; t + 4 <= e; t += 4) {
      int r0 = __builtin_amdgcn_readfirstlane(ebuf[t]);
      int r1 = __builtin_amdgcn_readfirstlane(ebuf[t + 1]);
      int r2 = __builtin_amdgcn_readfirstlane(ebuf[t + 2]);
      int r3 = __builtin_amdgcn_readfirstlane(ebuf[t + 3]);
      unsigned u0 = xwb[(size_t)r0 * 64 + lane];
      unsigned u1 = xwb[(size_t)r1 * 64 + lane];
      unsigned u2 = xwb[(size_t)r2 * 64 + lane];
      unsigned u3 = xwb[(size_t)r3 * 64 + lane];
      ax += bf16_lo(u0) + bf16_lo(u1) + bf16_lo(u2) + bf16_lo(u3);
      ay += bf16_hi(u0) + bf16_hi(u1) + bf16_hi(u2) + bf16_hi(u3);
    }
    for (; t < e; ++t) {
      int r = __builtin_amdgcn_readfirstlane(ebuf[t]);
      unsigned u = xwb[(size_t)r * 64 + lane];
      ax += bf16_lo(u);
      ay += bf16_hi(u);
    }
    float2 o;
    o.x = fmaxf(fmaf(ax, di, bgv.x), 0.f);
    o.y = fmaxf(fmaf(ay, di, bgv.y), 0.f);
    ((float2*)h2)[(size_t)i * 64 + lane] = o;
  }
}

// ---------------------------------------------------------------------------
static inline size_t align16(size_t x) { return (x + 15) & ~(size_t)15; }

extern "C" void kernel_launch(void* const* d_in, const int* in_sizes, int n_in,
                              void* d_out, int out_size, void* d_ws,
                              size_t ws_size, hipStream_t stream) {
  const float* z = (const float*)d_in[0];
  const float* W1 = (const float*)d_in[1];
  const float* b1 = (const float*)d_in[2];
  const float* Wg = (const float*)d_in[3];
  const float* bg = (const float*)d_in[4];
  const float* W2 = (const float*)d_in[5];
  const float* b2 = (const float*)d_in[6];
  const void* ei = d_in[7];

  int N = in_sizes[0] / HID;
  int E = in_sizes[7] / 2;
  int NBUCK = (N + 1023) >> 10;  // 49 for N=50000 (<= NBUCK_MAX)
  int TM = (N + 63) / 64;

  char* ws = (char*)d_ws;
  size_t szH = align16((size_t)N * HID * sizeof(float));
  size_t szXW = align16((size_t)N * 64 * sizeof(unsigned));
  float* h = (float*)ws;                  // [N,128] f32 (reused for h2)
  unsigned* xwb = (unsigned*)(ws + szH);  // [N,64] u32 = bf16[N,128]
  char* p = ws + szH + szXW;
  float* dinv = (float*)p;                   p += align16((size_t)N * 4);
  unsigned int* offsets = (unsigned int*)p;  p += align16((size_t)(N + 1) * 4);
  unsigned* recbuf = (unsigned*)p;           p += align16((size_t)E * 4);
  int* ebuf = (int*)p;                       p += align16((size_t)E * 4);
  int* flag = (int*)p;                       p += align16(4);
  unsigned* bucket_cnt = (unsigned*)p;       p += align16(NBUCK_MAX * 4);
  unsigned* bucket_base = (unsigned*)p;      p += align16((NBUCK_MAX + 1) * 4);
  unsigned* gcursor = (unsigned*)p;          p += align16(NBUCK_MAX * 4);
  unsigned* w1h = (unsigned*)p;              p += 2048 * 16;
  unsigned* w1l = (unsigned*)p;              p += 2048 * 16;
  unsigned* wgh = (unsigned*)p;              p += 2048 * 16;
  unsigned* wgl = (unsigned*)p;              p += 2048 * 16;
  unsigned* w2h = (unsigned*)p;              p += 1024 * 16;
  unsigned* w2l = (unsigned*)p;

  hipMemsetAsync(bucket_cnt, 0, NBUCK_MAX * 4, stream);

  detect_idx_kernel<<<1, 64, 0, stream>>>((const unsigned int*)ei, flag);

  // Weight fragment split (bf16 hi/lo, MFMA fragment order)
  wfrag_kernel<<<8, 256, 0, stream>>>(W1, w1h, w1l, 128);
  wfrag_kernel<<<8, 256, 0, stream>>>(Wg, wgh, wgl, 128);
  wfrag_kernel<<<4, 256, 0, stream>>>(W2, w2h, w2l, 64);

  // h = relu(z @ W1 + b1)
  mfma_gemm_kernel<128, 1, 0, 0>
      <<<2 * TM, 256, 0, stream>>>(z, w1h, w1l, b1, nullptr, h, N);

  // CSR build: bucket histogram -> scan -> binned record scatter -> per-
  // bucket counting sort (offsets/dinv/ebuf).
  bucket_count_kernel<<<512, 256, 0, stream>>>(ei, E, flag, bucket_cnt, NBUCK);
  bucket_scan_kernel<<<1, 64, 0, stream>>>(bucket_cnt, bucket_base, gcursor,
                                           offsets, NBUCK, N, E);
  bin_scatter_kernel<<<256, 256, 0, stream>>>(ei, E, flag, gcursor, recbuf,
                                              NBUCK);
  csr_build_kernel<<<NBUCK, 256, 0, stream>>>(recbuf, bucket_base, offsets,
                                              dinv, ebuf, N);

  // xwb = bf16( (h @ Wg) * dinv[row] )
  mfma_gemm_kernel<128, 0, 1, 0>
      <<<2 * TM, 256, 0, stream>>>(h, wgh, wgl, nullptr, dinv, xwb, N);

  // h2 = relu(agg * dinv + bg)   (overwrites h)
  agg_kernel<<<2048, 256, 0, stream>>>(xwb, dinv, offsets, ebuf, bg, h, N);

  // out = h2 @ W2 + b2, sigmoid col 0
  mfma_gemm_kernel<64, 0, 0, 1>
      <<<TM, 256, 0, stream>>>(h, w2h, w2l, b2, nullptr, (float*)d_out, N);
}

// Round 6
// 188.783 us; speedup vs baseline: 1.9999x; 1.9999x over previous
//
#include <hip/hip_runtime.h>
#include <hip/hip_bf16.h>
#include <math.h>

#define HID 128
#define ODIM 64
#define NSLICE 8

typedef __bf16 bf16x8 __attribute__((ext_vector_type(8)));
typedef float f32x4 __attribute__((ext_vector_type(4)));

union FragU {
  unsigned u[4];
  bf16x8 v;
};

// ---------------------------------------------------------------------------
// bf16 helpers (RNE)
// ---------------------------------------------------------------------------
__device__ inline unsigned pack_bf16(float a, float b) {
  unsigned ua = __float_as_uint(a), ub = __float_as_uint(b);
  ua += 0x7fffu + ((ua >> 16) & 1u);
  ub += 0x7fffu + ((ub >> 16) & 1u);
  return (ua >> 16) | (ub & 0xffff0000u);
}
__device__ inline float bf16_lo(unsigned u) { return __uint_as_float(u << 16); }
__device__ inline float bf16_hi(unsigned u) {
  return __uint_as_float(u & 0xffff0000u);
}
__device__ inline unsigned short bf16_of(float v) {
  unsigned uv = __float_as_uint(v);
  uv += 0x7fffu + ((uv >> 16) & 1u);
  return (unsigned short)(uv >> 16);
}

__device__ inline int edge_val(const void* ei, int is64, long long idx) {
  if (is64) return (int)((const long long*)ei)[idx];
  return ((const int*)ei)[idx];
}

// ---------------------------------------------------------------------------
// Convert edge_index (int32 or int64, detected per-wave from high words of
// the first 64 edges) into packed u16 pairs: rows32[j] = r(2j) | r(2j+1)<<16,
// cols32[j] likewise. Requires N <= 65536 (N = 50000).
// ---------------------------------------------------------------------------
__global__ __launch_bounds__(256) void convert_kernel(
    const void* __restrict__ ei, int E, unsigned* __restrict__ rows32,
    unsigned* __restrict__ cols32) {
  const unsigned* w = (const unsigned*)ei;
  int lane = threadIdx.x & 63;
  unsigned hv = w[2 * lane + 1];
  int is64 = (__ballot(hv == 0u) == 0xFFFFFFFFFFFFFFFFull) ? 1 : 0;
  int npair = (E + 1) >> 1;
  for (int j = blockIdx.x * 256 + threadIdx.x; j < npair;
       j += gridDim.x * 256) {
    int e0 = 2 * j, e1 = 2 * j + 1;
    unsigned r0 = (unsigned)edge_val(ei, is64, e0) & 0xFFFFu;
    unsigned c0 = (unsigned)edge_val(ei, is64, (long long)E + e0) & 0xFFFFu;
    unsigned r1 = 0, c1 = 0;
    if (e1 < E) {
      r1 = (unsigned)edge_val(ei, is64, e1) & 0xFFFFu;
      c1 = (unsigned)edge_val(ei, is64, (long long)E + e1) & 0xFFFFu;
    }
    rows32[j] = r0 | (r1 << 16);
    cols32[j] = c0 | (c1 << 16);
  }
}

// ---------------------------------------------------------------------------
// XCD-sliced in-degree count: blockIdx&7 selects a col-slice; each block
// scans the full col stream (L2/L3-resident u16) and atomics only into its
// slice of count[] -> count lines stay in one XCD's L2.
// ---------------------------------------------------------------------------
__global__ __launch_bounds__(256) void count_sliced_kernel(
    const unsigned* __restrict__ cols32, int E, unsigned* __restrict__ count,
    int slice_w) {
  int slice = blockIdx.x & (NSLICE - 1);
  int cid = blockIdx.x >> 3;
  int nch = gridDim.x >> 3;
  int lo = slice * slice_w, hi = lo + slice_w;
  int npair = (E + 1) >> 1;
  for (int j = cid * 256 + threadIdx.x; j < npair; j += nch * 256) {
    unsigned cc = cols32[j];
    int c0 = (int)(cc & 0xFFFFu), c1 = (int)(cc >> 16);
    if (c0 >= lo && c0 < hi) atomicAdd(&count[c0], 1u);
    if (2 * j + 1 < E && c1 >= lo && c1 < hi) atomicAdd(&count[c1], 1u);
  }
}

// ---------------------------------------------------------------------------
// 3-pass device-wide exclusive scan of count -> offsets (+cursor copy), dinv.
// ---------------------------------------------------------------------------
__global__ __launch_bounds__(256) void scan_part_kernel(
    const unsigned int* __restrict__ count, unsigned int* __restrict__ bsums,
    int n) {
  int base = blockIdx.x * 1024 + threadIdx.x * 4;
  unsigned int s = 0;
  if (base + 4 <= n) {
    uint4 c = *(const uint4*)&count[base];
    s = c.x + c.y + c.z + c.w;
  } else {
#pragma unroll
    for (int j = 0; j < 4; ++j) s += (base + j < n) ? count[base + j] : 0u;
  }
#pragma unroll
  for (int d = 32; d >= 1; d >>= 1) s += __shfl_down(s, d, 64);
  __shared__ unsigned int red[4];
  int wave = threadIdx.x >> 6, lane = threadIdx.x & 63;
  if (lane == 0) red[wave] = s;
  __syncthreads();
  if (threadIdx.x == 0) bsums[blockIdx.x] = red[0] + red[1] + red[2] + red[3];
}

__global__ void scan_top_kernel(const unsigned int* __restrict__ bsums,
                                unsigned int* __restrict__ bbase, int nb) {
  int t = threadIdx.x;  // 64 threads, single wave
  unsigned int run = 0;
  for (int s0 = 0; s0 < nb; s0 += 64) {
    unsigned int v = (s0 + t < nb) ? bsums[s0 + t] : 0u;
    unsigned int incl = v;
#pragma unroll
    for (int d = 1; d < 64; d <<= 1) {
      unsigned int u = __shfl_up(incl, d, 64);
      if (t >= d) incl += u;
    }
    if (s0 + t < nb) bbase[s0 + t] = run + incl - v;
    run += __shfl(incl, 63, 64);
  }
}

__global__ __launch_bounds__(256) void scan_final_kernel(
    const unsigned int* __restrict__ count,
    const unsigned int* __restrict__ bbase, unsigned int* __restrict__ offsets,
    unsigned int* __restrict__ cursor, float* __restrict__ dinv, int n,
    int E) {
  int base = blockIdx.x * 1024 + threadIdx.x * 4;
  unsigned int c[4];
  if (base + 4 <= n) {
    uint4 cv = *(const uint4*)&count[base];
    c[0] = cv.x; c[1] = cv.y; c[2] = cv.z; c[3] = cv.w;
  } else {
#pragma unroll
    for (int j = 0; j < 4; ++j) c[j] = (base + j < n) ? count[base + j] : 0u;
  }
  unsigned int tsum = c[0] + c[1] + c[2] + c[3];
  unsigned int incl = tsum;
#pragma unroll
  for (int d = 1; d < 64; d <<= 1) {
    unsigned int u = __shfl_up(incl, d, 64);
    if ((threadIdx.x & 63) >= d) incl += u;
  }
  __shared__ unsigned int wsum[4];
  int wave = threadIdx.x >> 6;
  if ((threadIdx.x & 63) == 63) wsum[wave] = incl;
  __syncthreads();
  unsigned int ex = bbase[blockIdx.x] + incl - tsum;
  for (int w = 0; w < wave; ++w) ex += wsum[w];
  unsigned int o[4];
  float dv[4];
#pragma unroll
  for (int j = 0; j < 4; ++j) {
    o[j] = ex;
    ex += c[j];
    dv[j] = rsqrtf((float)(1u + c[j]));
  }
  if (base + 4 <= n) {
    *(uint4*)&offsets[base] = make_uint4(o[0], o[1], o[2], o[3]);
    *(uint4*)&cursor[base] = make_uint4(o[0], o[1], o[2], o[3]);
    *(float4*)&dinv[base] = make_float4(dv[0], dv[1], dv[2], dv[3]);
  } else {
#pragma unroll
    for (int j = 0; j < 4; ++j)
      if (base + j < n) {
        offsets[base + j] = o[j];
        cursor[base + j] = o[j];
        dinv[base + j] = dv[j];
      }
  }
  if (blockIdx.x == 0 && threadIdx.x == 0) offsets[n] = (unsigned int)E;
}

// ---------------------------------------------------------------------------
// XCD-sliced CSR fill: cursor holds absolute write positions (init =
// offsets). Each slice's cursor/ebuf region is written by one XCD only;
// 2 B records halve line traffic vs int32.
// ---------------------------------------------------------------------------
__global__ __launch_bounds__(256) void fill_sliced_kernel(
    const unsigned* __restrict__ rows32, const unsigned* __restrict__ cols32,
    int E, unsigned* __restrict__ cursor, unsigned short* __restrict__ ebuf,
    int slice_w) {
  int slice = blockIdx.x & (NSLICE - 1);
  int cid = blockIdx.x >> 3;
  int nch = gridDim.x >> 3;
  int lo = slice * slice_w, hi = lo + slice_w;
  int npair = (E + 1) >> 1;
  for (int j = cid * 256 + threadIdx.x; j < npair; j += nch * 256) {
    unsigned rr = rows32[j];
    unsigned cc = cols32[j];
    int c0 = (int)(cc & 0xFFFFu), c1 = (int)(cc >> 16);
    if (c0 >= lo && c0 < hi) {
      unsigned p = atomicAdd(&cursor[c0], 1u);
      ebuf[p] = (unsigned short)(rr & 0xFFFFu);
    }
    if (2 * j + 1 < E && c1 >= lo && c1 < hi) {
      unsigned p = atomicAdd(&cursor[c1], 1u);
      ebuf[p] = (unsigned short)(rr >> 16);
    }
  }
}

// ---------------------------------------------------------------------------
// Split W1/Wg/W2 (f32 row-major) into bf16 hi/lo fragments in MFMA fragment
// order, all three in one launch (blocks 0-7: W1, 8-15: Wg, 16-19: W2).
// entry e: k = 32s + (lane>>4)*8 + i, col = t*16 + (lane&15),
// e = (t*4 + s)*64 + lane.
// ---------------------------------------------------------------------------
__global__ __launch_bounds__(256) void wfrag_all_kernel(
    const float* __restrict__ W1, const float* __restrict__ Wg,
    const float* __restrict__ W2, unsigned* __restrict__ w1h,
    unsigned* __restrict__ w1l, unsigned* __restrict__ wgh,
    unsigned* __restrict__ wgl, unsigned* __restrict__ w2h,
    unsigned* __restrict__ w2l) {
  int e = blockIdx.x * 256 + threadIdx.x;
  const float* W;
  unsigned *Wh, *Wl;
  int NC, eo;
  if (e < 2048) {
    W = W1; Wh = w1h; Wl = w1l; NC = 128; eo = e;
  } else if (e < 4096) {
    W = Wg; Wh = wgh; Wl = wgl; NC = 128; eo = e - 2048;
  } else if (e < 5120) {
    W = W2; Wh = w2h; Wl = w2l; NC = 64; eo = e - 4096;
  } else {
    return;
  }
  int lane = eo & 63;
  int s = (eo >> 6) & 3;
  int t = eo >> 8;
  int g = lane >> 4, c = lane & 15;
  int col = t * 16 + c;
  unsigned hw[4], lw[4];
#pragma unroll
  for (int j = 0; j < 4; ++j) {
    float a = W[(32 * s + g * 8 + 2 * j) * NC + col];
    float b = W[(32 * s + g * 8 + 2 * j + 1) * NC + col];
    unsigned h = pack_bf16(a, b);
    hw[j] = h;
    lw[j] = pack_bf16(a - bf16_lo(h), b - bf16_hi(h));
  }
  *(uint4*)&Wh[(size_t)eo * 4] = make_uint4(hw[0], hw[1], hw[2], hw[3]);
  *(uint4*)&Wl[(size_t)eo * 4] = make_uint4(lw[0], lw[1], lw[2], lw[3]);
}

// ---------------------------------------------------------------------------
// Split-bf16 MFMA GEMM:  out[M,NC] = A[M,128] @ W[128,NC], fp32-quality via
// D = Ah*Wh + Ah*Wl + Al*Wh. 4 waves = 64 rows x 64 cols; no LDS.
// ---------------------------------------------------------------------------
template <int NC, int RELU, int OBF16, int SIG0>
__global__ __launch_bounds__(256, 4) void mfma_gemm_kernel(
    const float* __restrict__ A, const unsigned* __restrict__ Whi,
    const unsigned* __restrict__ Wlo, const float* __restrict__ bias,
    const float* __restrict__ row_scale, void* __restrict__ out, int M) {
  int wave = threadIdx.x >> 6, lane = threadIdx.x & 63;
  int g = lane >> 4, c = lane & 15;
  int tiles_m = (M + 63) >> 6;
  int tiles_total = tiles_m * (NC / 64);
  for (int tid = blockIdx.x; tid < tiles_total; tid += gridDim.x) {
    int mt = tid % tiles_m;
    int half = tid / tiles_m;
    int r0 = mt * 64 + wave * 16;
    int rowc = min(r0 + c, M - 1);  // A-frag row = lane&15
    const float* ap = A + (size_t)rowc * 128 + g * 8;
    f32x4 fa[8];
#pragma unroll
    for (int s = 0; s < 4; ++s) {
      fa[2 * s] = *(const f32x4*)(ap + 32 * s);
      fa[2 * s + 1] = *(const f32x4*)(ap + 32 * s + 4);
    }
    f32x4 acc[4];
#pragma unroll
    for (int t = 0; t < 4; ++t) acc[t] = (f32x4){0.f, 0.f, 0.f, 0.f};
#pragma unroll
    for (int s = 0; s < 4; ++s) {
      FragU ah, al;
#pragma unroll
      for (int j = 0; j < 2; ++j) {
        f32x4 p = fa[2 * s + j];
        unsigned h0 = pack_bf16(p[0], p[1]);
        unsigned h1 = pack_bf16(p[2], p[3]);
        ah.u[2 * j] = h0;
        ah.u[2 * j + 1] = h1;
        al.u[2 * j] = pack_bf16(p[0] - bf16_lo(h0), p[1] - bf16_hi(h0));
        al.u[2 * j + 1] = pack_bf16(p[2] - bf16_lo(h1), p[3] - bf16_hi(h1));
      }
#pragma unroll
      for (int tl = 0; tl < 4; ++tl) {
        int e = ((half * 4 + tl) * 4 + s) * 64 + lane;
        FragU wh, wl;
        *(uint4*)wh.u = *(const uint4*)&Whi[(size_t)e * 4];
        *(uint4*)wl.u = *(const uint4*)&Wlo[(size_t)e * 4];
        acc[tl] = __builtin_amdgcn_mfma_f32_16x16x32_bf16(ah.v, wh.v, acc[tl],
                                                          0, 0, 0);
        acc[tl] = __builtin_amdgcn_mfma_f32_16x16x32_bf16(ah.v, wl.v, acc[tl],
                                                          0, 0, 0);
        acc[tl] = __builtin_amdgcn_mfma_f32_16x16x32_bf16(al.v, wh.v, acc[tl],
                                                          0, 0, 0);
      }
    }
    float rs[4];
    if (row_scale) {
#pragma unroll
      for (int r = 0; r < 4; ++r) rs[r] = row_scale[min(r0 + g * 4 + r, M - 1)];
    }
#pragma unroll
    for (int tl = 0; tl < 4; ++tl) {
      int colg = half * 64 + tl * 16 + c;
      float bv = bias ? bias[colg] : 0.f;
#pragma unroll
      for (int rg = 0; rg < 4; ++rg) {
        int r = r0 + g * 4 + rg;
        if (r < M) {
          float v = acc[tl][rg] + bv;
          if (RELU) v = fmaxf(v, 0.f);
          if (row_scale) v *= rs[rg];
          if (SIG0 && colg == 0) v = 1.f / (1.f + __expf(-v));
          if (OBF16) {
            ((unsigned short*)out)[(size_t)r * 128 + colg] = bf16_of(v);
          } else {
            ((float*)out)[(size_t)r * NC + colg] = v;
          }
        }
      }
    }
  }
}

// ---------------------------------------------------------------------------
// Aggregation: one wave per node. xwb is bf16 [N][128] (packed u32 [N][64]),
// PRE-SCALED by dinv[src]. h2 = relu((xwb[i] + sum_j xwb[j]) * dinv[i] + bg).
// ---------------------------------------------------------------------------
__global__ __launch_bounds__(256) void agg_kernel(
    const unsigned* __restrict__ xwb, const float* __restrict__ dinv,
    const unsigned int* __restrict__ offsets,
    const unsigned short* __restrict__ ebuf, const float* __restrict__ bg,
    float* __restrict__ h2, int n) {
  int lane = threadIdx.x & 63;
  int wid = (blockIdx.x * blockDim.x + threadIdx.x) >> 6;
  int nw = (gridDim.x * blockDim.x) >> 6;
  float2 bgv = ((const float2*)bg)[lane];
  for (int i = wid; i < n; i += nw) {
    float di = dinv[i];
    unsigned int s = offsets[i];
    unsigned int e = offsets[i + 1];
    unsigned uself = xwb[(size_t)i * 64 + lane];
    float ax = bf16_lo(uself), ay = bf16_hi(uself);
    unsigned int t = s;
    for (; t + 4 <= e; t += 4) {
      int r0 = __builtin_amdgcn_readfirstlane(ebuf[t]);
      int r1 = __builtin_amdgcn_readfirstlane(ebuf[t + 1]);
      int r2 = __builtin_amdgcn_readfirstlane(ebuf[t + 2]);
      int r3 = __builtin_amdgcn_readfirstlane(ebuf[t + 3]);
      unsigned u0 = xwb[(size_t)r0 * 64 + lane];
      unsigned u1 = xwb[(size_t)r1 * 64 + lane];
      unsigned u2 = xwb[(size_t)r2 * 64 + lane];
      unsigned u3 = xwb[(size_t)r3 * 64 + lane];
      ax += bf16_lo(u0) + bf16_lo(u1) + bf16_lo(u2) + bf16_lo(u3);
      ay += bf16_hi(u0) + bf16_hi(u1) + bf16_hi(u2) + bf16_hi(u3);
    }
    for (; t < e; ++t) {
      int r = __builtin_amdgcn_readfirstlane(ebuf[t]);
      unsigned u = xwb[(size_t)r * 64 + lane];
      ax += bf16_lo(u);
      ay += bf16_hi(u);
    }
    float2 o;
    o.x = fmaxf(fmaf(ax, di, bgv.x), 0.f);
    o.y = fmaxf(fmaf(ay, di, bgv.y), 0.f);
    ((float2*)h2)[(size_t)i * 64 + lane] = o;
  }
}

// ---------------------------------------------------------------------------
static inline size_t align16(size_t x) { return (x + 15) & ~(size_t)15; }

extern "C" void kernel_launch(void* const* d_in, const int* in_sizes, int n_in,
                              void* d_out, int out_size, void* d_ws,
                              size_t ws_size, hipStream_t stream) {
  const float* z = (const float*)d_in[0];
  const float* W1 = (const float*)d_in[1];
  const float* b1 = (const float*)d_in[2];
  const float* Wg = (const float*)d_in[3];
  const float* bg = (const float*)d_in[4];
  const float* W2 = (const float*)d_in[5];
  const float* b2 = (const float*)d_in[6];
  const void* ei = d_in[7];

  int N = in_sizes[0] / HID;
  int E = in_sizes[7] / 2;
  int NB = (N + 1023) / 1024;
  int TM = (N + 63) / 64;
  int SLICE_W = (N + NSLICE - 1) / NSLICE;
  int NPAIR = (E + 1) / 2;

  char* ws = (char*)d_ws;
  size_t szH = align16((size_t)N * HID * sizeof(float));
  size_t szXW = align16((size_t)N * 64 * sizeof(unsigned));
  float* h = (float*)ws;                  // [N,128] f32 (reused for h2)
  unsigned* xwb = (unsigned*)(ws + szH);  // [N,64] u32 = bf16[N,128]
  char* p = ws + szH + szXW;
  float* dinv = (float*)p;                   p += align16((size_t)N * 4);
  unsigned int* offsets = (unsigned int*)p;  p += align16((size_t)(N + 1) * 4);
  unsigned int* count = (unsigned int*)p;    p += align16((size_t)N * 4);
  unsigned int* cursor = (unsigned int*)p;   p += align16((size_t)N * 4);
  unsigned* rows32 = (unsigned*)p;           p += align16((size_t)NPAIR * 4);
  unsigned* cols32 = (unsigned*)p;           p += align16((size_t)NPAIR * 4);
  unsigned short* ebuf = (unsigned short*)p; p += align16((size_t)E * 2);
  unsigned int* bsums = (unsigned int*)p;    p += align16((size_t)NB * 4);
  unsigned int* bbase = (unsigned int*)p;    p += align16((size_t)NB * 4);
  unsigned* w1h = (unsigned*)p;              p += 2048 * 16;
  unsigned* w1l = (unsigned*)p;              p += 2048 * 16;
  unsigned* wgh = (unsigned*)p;              p += 2048 * 16;
  unsigned* wgl = (unsigned*)p;              p += 2048 * 16;
  unsigned* w2h = (unsigned*)p;              p += 1024 * 16;
  unsigned* w2l = (unsigned*)p;

  hipMemsetAsync(count, 0, (size_t)N * 4, stream);

  // Edge conversion to packed u16 (+ int64/int32 detection per wave)
  convert_kernel<<<512, 256, 0, stream>>>(ei, E, rows32, cols32);

  // Weight fragment split (bf16 hi/lo, MFMA fragment order), single launch
  wfrag_all_kernel<<<20, 256, 0, stream>>>(W1, Wg, W2, w1h, w1l, wgh, wgl,
                                           w2h, w2l);

  // h = relu(z @ W1 + b1)
  mfma_gemm_kernel<128, 1, 0, 0>
      <<<2 * TM, 256, 0, stream>>>(z, w1h, w1l, b1, nullptr, h, N);

  // CSR build: XCD-sliced count -> 3-pass scan -> XCD-sliced fill
  count_sliced_kernel<<<2048, 256, 0, stream>>>(cols32, E, count, SLICE_W);
  scan_part_kernel<<<NB, 256, 0, stream>>>(count, bsums, N);
  scan_top_kernel<<<1, 64, 0, stream>>>(bsums, bbase, NB);
  scan_final_kernel<<<NB, 256, 0, stream>>>(count, bbase, offsets, cursor,
                                            dinv, N, E);
  fill_sliced_kernel<<<2048, 256, 0, stream>>>(rows32, cols32, E, cursor, ebuf,
                                               SLICE_W);

  // xwb = bf16( (h @ Wg) * dinv[row] )
  mfma_gemm_kernel<128, 0, 1, 0>
      <<<2 * TM, 256, 0, stream>>>(h, wgh, wgl, nullptr, dinv, xwb, N);

  // h2 = relu(agg * dinv + bg)   (overwrites h)
  agg_kernel<<<2048, 256, 0, stream>>>(xwb, dinv, offsets, ebuf, bg, h, N);

  // out = h2 @ W2 + b2, sigmoid col 0
  mfma_gemm_kernel<64, 0, 0, 1>
      <<<TM, 256, 0, stream>>>(h, w2h, w2l, b2, nullptr, (float*)d_out, N);
}